// Round 1
// baseline (2489.877 us; speedup 1.0000x reference)
//
#include <hip/hip_runtime.h>
#include <math.h>

// Problem constants
#define TB 4
#define TS 2048
#define TE 1024
#define TH 16
#define TD 64
#define TM_ (TB*TS)   // 8192 rows

// Workspace float offsets (total 17,170,432 floats = 68.7 MB)
#define WS_Q   0
#define WS_K   8388608
#define WS_M   16777216
#define WS_L   16908288
#define WS_TAB 17039360

// ----------------------------------------------------------------------------
// GEMM: C[m,n] = sum_k X[m,k] * W[n,k] + bias[n]    (X:[M=8192,K=1024], W:[N=1024,K=1024])
// MODE 0: out[m*N + n]   (row-major [B,S,E])
// MODE 1: out[((b*TH + h)*TS + s)*TD + d]  with b=m>>11, s=m&2047, h=n>>6, d=n&63
// 128x128 tile, BK=16, 256 threads, 8x8 per thread (AI = 1 FMA / LDS byte).
// ----------------------------------------------------------------------------
template<int MODE>
__global__ __launch_bounds__(256, 2)
void gemm_nt(const float* __restrict__ X, const float* __restrict__ W,
             const float* __restrict__ bias, float* __restrict__ out)
{
    __shared__ float As[16][132];   // k-major, stride 132 keeps f4 reads aligned + banks spread
    __shared__ float Bs[16][132];
    const int tid = threadIdx.x;
    const int tx = tid & 15, ty = tid >> 4;
    const int m0 = blockIdx.y * 128;
    const int n0 = blockIdx.x * 128;
    const int K = TE, N = TE;

    float acc[8][8];
    #pragma unroll
    for (int i = 0; i < 8; ++i)
        #pragma unroll
        for (int j = 0; j < 8; ++j) acc[i][j] = 0.f;

    for (int kt = 0; kt < K; kt += 16) {
        #pragma unroll
        for (int i = 0; i < 2; ++i) {
            const int f = tid + 256 * i;          // 512 float4s per tile side
            const int row = f >> 2;               // 4 f4 per row
            const int kq = (f & 3) * 4;
            float4 av = *(const float4*)(X + (size_t)(m0 + row) * K + kt + kq);
            As[kq + 0][row] = av.x; As[kq + 1][row] = av.y;
            As[kq + 2][row] = av.z; As[kq + 3][row] = av.w;
            float4 bv = *(const float4*)(W + (size_t)(n0 + row) * K + kt + kq);
            Bs[kq + 0][row] = bv.x; Bs[kq + 1][row] = bv.y;
            Bs[kq + 2][row] = bv.z; Bs[kq + 3][row] = bv.w;
        }
        __syncthreads();
        #pragma unroll
        for (int kk = 0; kk < 16; ++kk) {
            float4 a0 = *(const float4*)&As[kk][4 * ty];
            float4 a1 = *(const float4*)&As[kk][64 + 4 * ty];
            float4 b0 = *(const float4*)&Bs[kk][4 * tx];
            float4 b1 = *(const float4*)&Bs[kk][64 + 4 * tx];
            float a[8]  = {a0.x, a0.y, a0.z, a0.w, a1.x, a1.y, a1.z, a1.w};
            float bb[8] = {b0.x, b0.y, b0.z, b0.w, b1.x, b1.y, b1.z, b1.w};
            #pragma unroll
            for (int i = 0; i < 8; ++i)
                #pragma unroll
                for (int j = 0; j < 8; ++j)
                    acc[i][j] = fmaf(a[i], bb[j], acc[i][j]);
        }
        __syncthreads();
    }

    #pragma unroll
    for (int i = 0; i < 8; ++i) {
        const int r = m0 + ((i < 4) ? (4 * ty + i) : (64 + 4 * ty + i - 4));
        #pragma unroll
        for (int jg = 0; jg < 2; ++jg) {
            const int cl = jg * 64 + 4 * tx;
            const int n = n0 + cl;
            float4 bv = *(const float4*)(bias + n);
            float4 v;
            v.x = acc[i][jg * 4 + 0] + bv.x;
            v.y = acc[i][jg * 4 + 1] + bv.y;
            v.z = acc[i][jg * 4 + 2] + bv.z;
            v.w = acc[i][jg * 4 + 3] + bv.w;
            if (MODE == 0) {
                *(float4*)(out + (size_t)r * N + n) = v;
            } else {
                const int bb_ = r >> 11, s = r & 2047;
                const int h = n >> 6, d = n & 63;
                *(float4*)(out + ((size_t)(bb_ * TH + h) * TS + s) * TD + d) = v;
            }
        }
    }
}

// ----------------------------------------------------------------------------
// RoPE: precompute cos/sin table [S][32][2], then apply in-place to Q and K
// (layout [B,H,S,D]).  q'[d] = q[d]*c - q[d+32]*sn ; q'[d+32] = q[d+32]*c + q[d]*sn
// ----------------------------------------------------------------------------
__global__ void rope_table(float* __restrict__ tab)
{
    const int idx = blockIdx.x * 256 + threadIdx.x;   // 65536 = S*32
    const int d = idx & 31, s = idx >> 5;
    const float e = (float)(2 * d) / 64.0f;           // matches arange(0,64,2)/64
    const float inv = 1.0f / powf(10000.0f, e);
    const float a = (float)s * inv;
    tab[2 * idx + 0] = cosf(a);
    tab[2 * idx + 1] = sinf(a);
}

__global__ void rope_apply(float* __restrict__ Q, float* __restrict__ Kv,
                           const float* __restrict__ tab)
{
    const int idx = blockIdx.x * 256 + threadIdx.x;   // 8,388,608 threads
    const int half = TB * TH * TS * 32;               // 4,194,304 (2^22)
    float* P = (idx < half) ? Q : Kv;
    const int u = idx & (half - 1);
    const int d = u & 31;
    const int s = (u >> 5) & 2047;
    const int bh = u >> 16;
    const size_t base = (size_t)bh * (TS * TD) + (size_t)s * TD;
    const float c  = tab[2 * (s * 32 + d) + 0];
    const float sn = tab[2 * (s * 32 + d) + 1];
    const float x0 = P[base + d], x1 = P[base + d + 32];
    P[base + d]      = x0 * c - x1 * sn;
    P[base + d + 32] = x1 * c + x0 * sn;
}

// ----------------------------------------------------------------------------
// Flash attention forward per (b, h, 64-row q-tile): online softmax over 64-col
// K chunks; P round-trips through LDS for the PV product; saves per-row m, l.
// Scale (1/8) is folded into the Q staging.
// ----------------------------------------------------------------------------
__global__ __launch_bounds__(256, 2)
void attn_flash(const float* __restrict__ Q, const float* __restrict__ Kg,
                const float* __restrict__ V, float* __restrict__ O,
                float* __restrict__ Ms, float* __restrict__ Ls)
{
    __shared__ float Qt[64][68];   // [d][q], scaled
    __shared__ float Kt[64][68];   // [d][j]
    __shared__ float Vt[64][68];   // [j][d]
    __shared__ float Ps[64][68];   // [q][j]
    const int tid = threadIdx.x, tx = tid & 15, ty = tid >> 4;
    const int q0 = blockIdx.x * 64;
    const int h = blockIdx.y, b = blockIdx.z;
    const size_t hoff = (size_t)(b * TH + h) * TS * TD;
    const float* Qh = Q + hoff;
    const float* Kh = Kg + hoff;
    const float* Vh = V + hoff;

    #pragma unroll
    for (int i = 0; i < 4; ++i) {
        const int f = tid + 256 * i;
        const int row = f >> 4;
        const int dq = (f & 15) * 4;
        float4 qv = *(const float4*)(Qh + (size_t)(q0 + row) * TD + dq);
        Qt[dq + 0][row] = qv.x * 0.125f;
        Qt[dq + 1][row] = qv.y * 0.125f;
        Qt[dq + 2][row] = qv.z * 0.125f;
        Qt[dq + 3][row] = qv.w * 0.125f;
    }

    float m_i[4], l_i[4], o_acc[4][4];
    #pragma unroll
    for (int i = 0; i < 4; ++i) {
        m_i[i] = -1e30f; l_i[i] = 0.f;
        #pragma unroll
        for (int c = 0; c < 4; ++c) o_acc[i][c] = 0.f;
    }

    for (int j0 = 0; j0 < TS; j0 += 64) {
        __syncthreads();   // previous iter's PV reads done (also publishes Qt on iter 0)
        #pragma unroll
        for (int i = 0; i < 4; ++i) {
            const int f = tid + 256 * i;
            const int row = f >> 4;
            const int dq = (f & 15) * 4;
            float4 kv = *(const float4*)(Kh + (size_t)(j0 + row) * TD + dq);
            Kt[dq + 0][row] = kv.x; Kt[dq + 1][row] = kv.y;
            Kt[dq + 2][row] = kv.z; Kt[dq + 3][row] = kv.w;
            float4 vv = *(const float4*)(Vh + (size_t)(j0 + row) * TD + dq);
            *(float4*)&Vt[row][dq] = vv;
        }
        __syncthreads();

        float sc[4][4];
        #pragma unroll
        for (int i = 0; i < 4; ++i)
            #pragma unroll
            for (int j = 0; j < 4; ++j) sc[i][j] = 0.f;

        #pragma unroll 16
        for (int kk = 0; kk < 64; ++kk) {
            float4 qa = *(const float4*)&Qt[kk][4 * ty];
            float4 kb = *(const float4*)&Kt[kk][4 * tx];
            float a[4]  = {qa.x, qa.y, qa.z, qa.w};
            float bb[4] = {kb.x, kb.y, kb.z, kb.w};
            #pragma unroll
            for (int i = 0; i < 4; ++i)
                #pragma unroll
                for (int j = 0; j < 4; ++j)
                    sc[i][j] = fmaf(a[i], bb[j], sc[i][j]);
        }

        #pragma unroll
        for (int i = 0; i < 4; ++i) {
            float mx = fmaxf(fmaxf(sc[i][0], sc[i][1]), fmaxf(sc[i][2], sc[i][3]));
            #pragma unroll
            for (int off = 8; off > 0; off >>= 1)
                mx = fmaxf(mx, __shfl_xor(mx, off, 16));
            const float mnew = fmaxf(m_i[i], mx);
            const float alpha = __expf(m_i[i] - mnew);
            float p[4], rs = 0.f;
            #pragma unroll
            for (int c = 0; c < 4; ++c) { p[c] = __expf(sc[i][c] - mnew); rs += p[c]; }
            #pragma unroll
            for (int off = 8; off > 0; off >>= 1)
                rs += __shfl_xor(rs, off, 16);
            l_i[i] = l_i[i] * alpha + rs;
            m_i[i] = mnew;
            #pragma unroll
            for (int c = 0; c < 4; ++c) o_acc[i][c] *= alpha;
            *(float4*)&Ps[4 * ty + i][4 * tx] = make_float4(p[0], p[1], p[2], p[3]);
        }
        __syncthreads();   // Ps visible to all tx of each row

        #pragma unroll 8
        for (int j = 0; j < 64; ++j) {
            float4 vv = *(const float4*)&Vt[j][4 * tx];
            #pragma unroll
            for (int i = 0; i < 4; ++i) {
                const float pv = Ps[4 * ty + i][j];
                o_acc[i][0] = fmaf(pv, vv.x, o_acc[i][0]);
                o_acc[i][1] = fmaf(pv, vv.y, o_acc[i][1]);
                o_acc[i][2] = fmaf(pv, vv.z, o_acc[i][2]);
                o_acc[i][3] = fmaf(pv, vv.w, o_acc[i][3]);
            }
        }
    }

    #pragma unroll
    for (int i = 0; i < 4; ++i) {
        const int r = q0 + 4 * ty + i;
        const float inv = 1.0f / l_i[i];
        float4 v = make_float4(o_acc[i][0] * inv, o_acc[i][1] * inv,
                               o_acc[i][2] * inv, o_acc[i][3] * inv);
        // write pre-projection output in [B,S,E] layout
        *(float4*)(O + ((size_t)(b * TS) + r) * TE + h * TD + 4 * tx) = v;
        if (tx == 0) {
            Ms[(size_t)(b * TH + h) * TS + r] = m_i[i];
            Ls[(size_t)(b * TH + h) * TS + r] = l_i[i];
        }
    }
}

// ----------------------------------------------------------------------------
// attn_avg: per (b, 128-q-tile, 128-j-tile), loop all 16 heads, recompute the
// score tile, p = exp(s - m)/l using saved stats, accumulate, write mean/16.
// ----------------------------------------------------------------------------
__global__ __launch_bounds__(256, 2)
void attn_avg_k(const float* __restrict__ Q, const float* __restrict__ Kg,
                const float* __restrict__ Ms, const float* __restrict__ Ls,
                float* __restrict__ AV)
{
    __shared__ float Qt[64][132];   // [d][q], scaled
    __shared__ float Kt[64][132];   // [d][j]
    const int tid = threadIdx.x, tx = tid & 15, ty = tid >> 4;
    const int j0 = blockIdx.x * 128;
    const int q0 = blockIdx.y * 128;
    const int b = blockIdx.z;

    float acc[8][8];
    #pragma unroll
    for (int i = 0; i < 8; ++i)
        #pragma unroll
        for (int j = 0; j < 8; ++j) acc[i][j] = 0.f;

    for (int h = 0; h < TH; ++h) {
        __syncthreads();   // previous head's reads done
        const size_t hoff = (size_t)(b * TH + h) * TS * TD;
        #pragma unroll
        for (int i = 0; i < 8; ++i) {
            const int f = tid + 256 * i;     // 2048 f4 per tile
            const int row = f >> 4;
            const int dq = (f & 15) * 4;
            float4 qv = *(const float4*)(Q + hoff + (size_t)(q0 + row) * TD + dq);
            Qt[dq + 0][row] = qv.x * 0.125f;
            Qt[dq + 1][row] = qv.y * 0.125f;
            Qt[dq + 2][row] = qv.z * 0.125f;
            Qt[dq + 3][row] = qv.w * 0.125f;
            float4 kv = *(const float4*)(Kg + hoff + (size_t)(j0 + row) * TD + dq);
            Kt[dq + 0][row] = kv.x; Kt[dq + 1][row] = kv.y;
            Kt[dq + 2][row] = kv.z; Kt[dq + 3][row] = kv.w;
        }
        __syncthreads();

        float sc[8][8];
        #pragma unroll
        for (int i = 0; i < 8; ++i)
            #pragma unroll
            for (int j = 0; j < 8; ++j) sc[i][j] = 0.f;

        #pragma unroll 8
        for (int kk = 0; kk < 64; ++kk) {
            float4 a0 = *(const float4*)&Qt[kk][4 * ty];
            float4 a1 = *(const float4*)&Qt[kk][64 + 4 * ty];
            float4 b0 = *(const float4*)&Kt[kk][4 * tx];
            float4 b1 = *(const float4*)&Kt[kk][64 + 4 * tx];
            float a[8]  = {a0.x, a0.y, a0.z, a0.w, a1.x, a1.y, a1.z, a1.w};
            float bb[8] = {b0.x, b0.y, b0.z, b0.w, b1.x, b1.y, b1.z, b1.w};
            #pragma unroll
            for (int i = 0; i < 8; ++i)
                #pragma unroll
                for (int j = 0; j < 8; ++j)
                    sc[i][j] = fmaf(a[i], bb[j], sc[i][j]);
        }

        #pragma unroll
        for (int i = 0; i < 8; ++i) {
            const int r = q0 + ((i < 4) ? (4 * ty + i) : (64 + 4 * ty + i - 4));
            const float mm = Ms[(size_t)(b * TH + h) * TS + r];
            const float il = 1.0f / Ls[(size_t)(b * TH + h) * TS + r];
            #pragma unroll
            for (int j = 0; j < 8; ++j)
                acc[i][j] += __expf(sc[i][j] - mm) * il;
        }
    }

    const float inv_h = 1.0f / (float)TH;
    #pragma unroll
    for (int i = 0; i < 8; ++i) {
        const int r = q0 + ((i < 4) ? (4 * ty + i) : (64 + 4 * ty + i - 4));
        #pragma unroll
        for (int jg = 0; jg < 2; ++jg) {
            const int c = j0 + jg * 64 + 4 * tx;
            float4 v = make_float4(acc[i][jg * 4 + 0] * inv_h, acc[i][jg * 4 + 1] * inv_h,
                                   acc[i][jg * 4 + 2] * inv_h, acc[i][jg * 4 + 3] * inv_h);
            *(float4*)(AV + ((size_t)b * TS + r) * TS + c) = v;
        }
    }
}

// ----------------------------------------------------------------------------
extern "C" void kernel_launch(void* const* d_in, const int* in_sizes, int n_in,
                              void* d_out, int out_size, void* d_ws, size_t ws_size,
                              hipStream_t stream)
{
    const float* query = (const float*)d_in[0];
    const float* key   = (const float*)d_in[1];
    const float* value = (const float*)d_in[2];
    const float* Wq = (const float*)d_in[3];
    const float* bq = (const float*)d_in[4];
    const float* Wk = (const float*)d_in[5];
    const float* bk = (const float*)d_in[6];
    const float* Wv = (const float*)d_in[7];
    const float* bv = (const float*)d_in[8];
    const float* Wo = (const float*)d_in[9];
    const float* bo = (const float*)d_in[10];

    float* ws  = (float*)d_ws;
    float* Qr  = ws + WS_Q;       // RoPE'd Q, [B,H,S,D]
    float* Kr  = ws + WS_K;       // RoPE'd K, [B,H,S,D]
    float* Msf = ws + WS_M;       // row max   [B,H,S]
    float* Lsf = ws + WS_L;       // row sum   [B,H,S]
    float* tab = ws + WS_TAB;     // cos/sin   [S,32,2]

    float* out  = (float*)d_out;                        // [B,S,E]
    float* attn = out + (size_t)TB * TS * TE;           // [B,S,S]
    // Park V and pre-projection O in the attn_avg output region; both are dead
    // by the time attn_avg_k (the final writer of that region) runs.
    float* Vr = attn;                                   // 8.4M floats
    float* Ow = attn + (size_t)TB * TS * TE;            // 8.4M floats

    dim3 blk(256);
    dim3 gproj(TE / 128, TM_ / 128);

    gemm_nt<1><<<gproj, blk, 0, stream>>>(query, Wq, bq, Qr);
    gemm_nt<1><<<gproj, blk, 0, stream>>>(key,   Wk, bk, Kr);
    gemm_nt<1><<<gproj, blk, 0, stream>>>(value, Wv, bv, Vr);
    rope_table<<<dim3(256), blk, 0, stream>>>(tab);
    rope_apply<<<dim3(32768), blk, 0, stream>>>(Qr, Kr, tab);
    attn_flash<<<dim3(TS / 64, TH, TB), blk, 0, stream>>>(Qr, Kr, Vr, Ow, Msf, Lsf);
    gemm_nt<0><<<gproj, blk, 0, stream>>>(Ow, Wo, bo, out);          // before attn_avg!
    attn_avg_k<<<dim3(TS / 128, TS / 128, TB), blk, 0, stream>>>(Qr, Kr, Msf, Lsf, attn);
}

// Round 2
// 1850.555 us; speedup vs baseline: 1.3455x; 1.3455x over previous
//
#include <hip/hip_runtime.h>
#include <math.h>

// Problem constants
#define TB 4
#define TS 2048
#define TE 1024
#define TH 16
#define TD 64
#define TM_ (TB*TS)   // 8192 rows

// Workspace float offsets
#define WS_Q   0
#define WS_K   8388608
#define WS_M   16777216
#define WS_L   16908288
#define WS_TAB 17039360

typedef __attribute__((ext_vector_type(8))) short bf16x8;  // 8 bf16 = 4 VGPRs
typedef __attribute__((ext_vector_type(4))) float f32x4;

static __device__ inline short f2bf(float x) {
    union { float f; unsigned u; } v; v.f = x;
    unsigned r = v.u + 0x7fff + ((v.u >> 16) & 1);   // RNE
    return (short)(r >> 16);
}

// ----------------------------------------------------------------------------
// GEMM: C[m,n] = sum_k X[m,k] * W[n,k] + bias[n]  (fp32 VALU, unchanged R0)
// ----------------------------------------------------------------------------
template<int MODE>
__global__ __launch_bounds__(256, 2)
void gemm_nt(const float* __restrict__ X, const float* __restrict__ W,
             const float* __restrict__ bias, float* __restrict__ out)
{
    __shared__ float As[16][132];
    __shared__ float Bs[16][132];
    const int tid = threadIdx.x;
    const int tx = tid & 15, ty = tid >> 4;
    const int m0 = blockIdx.y * 128;
    const int n0 = blockIdx.x * 128;
    const int K = TE, N = TE;

    float acc[8][8];
    #pragma unroll
    for (int i = 0; i < 8; ++i)
        #pragma unroll
        for (int j = 0; j < 8; ++j) acc[i][j] = 0.f;

    for (int kt = 0; kt < K; kt += 16) {
        #pragma unroll
        for (int i = 0; i < 2; ++i) {
            const int f = tid + 256 * i;
            const int row = f >> 2;
            const int kq = (f & 3) * 4;
            float4 av = *(const float4*)(X + (size_t)(m0 + row) * K + kt + kq);
            As[kq + 0][row] = av.x; As[kq + 1][row] = av.y;
            As[kq + 2][row] = av.z; As[kq + 3][row] = av.w;
            float4 bv = *(const float4*)(W + (size_t)(n0 + row) * K + kt + kq);
            Bs[kq + 0][row] = bv.x; Bs[kq + 1][row] = bv.y;
            Bs[kq + 2][row] = bv.z; Bs[kq + 3][row] = bv.w;
        }
        __syncthreads();
        #pragma unroll
        for (int kk = 0; kk < 16; ++kk) {
            float4 a0 = *(const float4*)&As[kk][4 * ty];
            float4 a1 = *(const float4*)&As[kk][64 + 4 * ty];
            float4 b0 = *(const float4*)&Bs[kk][4 * tx];
            float4 b1 = *(const float4*)&Bs[kk][64 + 4 * tx];
            float a[8]  = {a0.x, a0.y, a0.z, a0.w, a1.x, a1.y, a1.z, a1.w};
            float bb[8] = {b0.x, b0.y, b0.z, b0.w, b1.x, b1.y, b1.z, b1.w};
            #pragma unroll
            for (int i = 0; i < 8; ++i)
                #pragma unroll
                for (int j = 0; j < 8; ++j)
                    acc[i][j] = fmaf(a[i], bb[j], acc[i][j]);
        }
        __syncthreads();
    }

    #pragma unroll
    for (int i = 0; i < 8; ++i) {
        const int r = m0 + ((i < 4) ? (4 * ty + i) : (64 + 4 * ty + i - 4));
        #pragma unroll
        for (int jg = 0; jg < 2; ++jg) {
            const int cl = jg * 64 + 4 * tx;
            const int n = n0 + cl;
            float4 bv = *(const float4*)(bias + n);
            float4 v;
            v.x = acc[i][jg * 4 + 0] + bv.x;
            v.y = acc[i][jg * 4 + 1] + bv.y;
            v.z = acc[i][jg * 4 + 2] + bv.z;
            v.w = acc[i][jg * 4 + 3] + bv.w;
            if (MODE == 0) {
                *(float4*)(out + (size_t)r * N + n) = v;
            } else {
                const int bb_ = r >> 11, s = r & 2047;
                const int h = n >> 6, d = n & 63;
                *(float4*)(out + ((size_t)(bb_ * TH + h) * TS + s) * TD + d) = v;
            }
        }
    }
}

// ----------------------------------------------------------------------------
// RoPE (unchanged)
// ----------------------------------------------------------------------------
__global__ void rope_table(float* __restrict__ tab)
{
    const int idx = blockIdx.x * 256 + threadIdx.x;
    const int d = idx & 31, s = idx >> 5;
    const float e = (float)(2 * d) / 64.0f;
    const float inv = 1.0f / powf(10000.0f, e);
    const float a = (float)s * inv;
    tab[2 * idx + 0] = cosf(a);
    tab[2 * idx + 1] = sinf(a);
}

__global__ void rope_apply(float* __restrict__ Q, float* __restrict__ Kv,
                           const float* __restrict__ tab)
{
    const int idx = blockIdx.x * 256 + threadIdx.x;
    const int half = TB * TH * TS * 32;
    float* P = (idx < half) ? Q : Kv;
    const int u = idx & (half - 1);
    const int d = u & 31;
    const int s = (u >> 5) & 2047;
    const int bh = u >> 16;
    const size_t base = (size_t)bh * (TS * TD) + (size_t)s * TD;
    const float c  = tab[2 * (s * 32 + d) + 0];
    const float sn = tab[2 * (s * 32 + d) + 1];
    const float x0 = P[base + d], x1 = P[base + d + 32];
    P[base + d]      = x0 * c - x1 * sn;
    P[base + d + 32] = x1 * c + x0 * sn;
}

// ----------------------------------------------------------------------------
// Flash attention with MFMA.
// Block: 256 thr = 4 waves; q-tile 64 rows (16 per wave); j-tiles of 64.
// QK^T: split-bf16 (qh*kh + qh*kl + ql*kh) -> ~fp32 accuracy.
// PV:   hi-only bf16 P and V (errors average over 2048-key softmax sum).
// Layouts (m89/m91): A[m=lane&15][k=quad*8+j], B[k=quad*8+j][n=lane&15],
//                    C[col=lane&15][row=quad*4+reg].
// ----------------------------------------------------------------------------
__global__ __launch_bounds__(256, 2)
void attn_flash(const float* __restrict__ Q, const float* __restrict__ Kg,
                const float* __restrict__ V, float* __restrict__ O,
                float* __restrict__ Ms, float* __restrict__ Ls)
{
    // +8 bf16 row pad (144B rows): keeps b128 frag reads bank-spread & aligned
    __shared__ short Qh[64][72], Ql[64][72];
    __shared__ short Kh[64][72], Kl[64][72];
    __shared__ short Vt[64][72];            // V^T: [d][j]
    __shared__ short Ps[64][72];            // P:   [q][j]

    const int tid  = threadIdx.x;
    const int lane = tid & 63;
    const int wv   = tid >> 6;        // wave 0..3
    const int t16  = lane & 15;
    const int quad = lane >> 4;
    const int q0w  = wv * 16;         // wave's q-row base within tile

    const int q0 = blockIdx.x * 64;
    const int h = blockIdx.y, b = blockIdx.z;
    const size_t hoff = (size_t)(b * TH + h) * TS * TD;
    const float* Qg = Q + hoff;
    const float* Kh_g = Kg + hoff;
    const float* Vg = V + hoff;

    // ---- stage Q (scaled by 1/8, split hi/lo) ----
    #pragma unroll
    for (int i = 0; i < 4; ++i) {
        const int f = tid + 256 * i;          // 1024 float4
        const int row = f >> 4;
        const int dq = (f & 15) * 4;
        float4 qv = *(const float4*)(Qg + (size_t)(q0 + row) * TD + dq);
        float x[4] = {qv.x * 0.125f, qv.y * 0.125f, qv.z * 0.125f, qv.w * 0.125f};
        short hs[4], ls[4];
        #pragma unroll
        for (int c = 0; c < 4; ++c) {
            hs[c] = f2bf(x[c]);
            union { unsigned u; float f; } bk; bk.u = ((unsigned)(unsigned short)hs[c]) << 16;
            ls[c] = f2bf(x[c] - bk.f);
        }
        *(short4*)&Qh[row][dq] = make_short4(hs[0], hs[1], hs[2], hs[3]);
        *(short4*)&Ql[row][dq] = make_short4(ls[0], ls[1], ls[2], ls[3]);
    }
    __syncthreads();

    // per-wave Q fragments (2 ksteps x hi/lo)
    bf16x8 qfh[2], qfl[2];
    #pragma unroll
    for (int ks = 0; ks < 2; ++ks) {
        qfh[ks] = *(const bf16x8*)&Qh[q0w + t16][ks * 32 + quad * 8];
        qfl[ks] = *(const bf16x8*)&Ql[q0w + t16][ks * 32 + quad * 8];
    }

    float m_i[4], l_i[4];
    f32x4 o_acc[4];
    #pragma unroll
    for (int r = 0; r < 4; ++r) { m_i[r] = -1e30f; l_i[r] = 0.f; }
    #pragma unroll
    for (int dt = 0; dt < 4; ++dt) o_acc[dt] = (f32x4){0.f, 0.f, 0.f, 0.f};

    for (int j0 = 0; j0 < TS; j0 += 64) {
        __syncthreads();   // prev iter's PV reads of Vt done
        // ---- stage K (split hi/lo) ----
        #pragma unroll
        for (int i = 0; i < 4; ++i) {
            const int f = tid + 256 * i;
            const int row = f >> 4;
            const int dq = (f & 15) * 4;
            float4 kv = *(const float4*)(Kh_g + (size_t)(j0 + row) * TD + dq);
            float x[4] = {kv.x, kv.y, kv.z, kv.w};
            short hs[4], ls[4];
            #pragma unroll
            for (int c = 0; c < 4; ++c) {
                hs[c] = f2bf(x[c]);
                union { unsigned u; float f; } bk; bk.u = ((unsigned)(unsigned short)hs[c]) << 16;
                ls[c] = f2bf(x[c] - bk.f);
            }
            *(short4*)&Kh[row][dq] = make_short4(hs[0], hs[1], hs[2], hs[3]);
            *(short4*)&Kl[row][dq] = make_short4(ls[0], ls[1], ls[2], ls[3]);
        }
        // ---- stage V transposed (hi only) ----
        #pragma unroll
        for (int i = 0; i < 4; ++i) {
            const int f = tid + 256 * i;
            const int t_ = f & 15;
            const int qd = (f >> 4) & 3;
            const int s_ = f >> 6;                 // 0..15 across tid-high + i
            const int vrow = t_ + 16 * (s_ & 3);
            const int vq = qd + 4 * (s_ >> 2);
            float4 vv = *(const float4*)(Vg + (size_t)(j0 + vrow) * TD + vq * 4);
            Vt[vq * 4 + 0][vrow] = f2bf(vv.x);
            Vt[vq * 4 + 1][vrow] = f2bf(vv.y);
            Vt[vq * 4 + 2][vrow] = f2bf(vv.z);
            Vt[vq * 4 + 3][vrow] = f2bf(vv.w);
        }
        __syncthreads();

        // ---- scores: 4 j-tiles x 2 ksteps x 3 split terms ----
        f32x4 sc[4];
        #pragma unroll
        for (int t = 0; t < 4; ++t) sc[t] = (f32x4){0.f, 0.f, 0.f, 0.f};
        #pragma unroll
        for (int t = 0; t < 4; ++t) {
            #pragma unroll
            for (int ks = 0; ks < 2; ++ks) {
                bf16x8 kf_h = *(const bf16x8*)&Kh[t * 16 + t16][ks * 32 + quad * 8];
                bf16x8 kf_l = *(const bf16x8*)&Kl[t * 16 + t16][ks * 32 + quad * 8];
                sc[t] = __builtin_amdgcn_mfma_f32_16x16x32_bf16(qfh[ks], kf_h, sc[t], 0, 0, 0);
                sc[t] = __builtin_amdgcn_mfma_f32_16x16x32_bf16(qfh[ks], kf_l, sc[t], 0, 0, 0);
                sc[t] = __builtin_amdgcn_mfma_f32_16x16x32_bf16(qfl[ks], kf_h, sc[t], 0, 0, 0);
            }
        }

        // ---- online softmax (C layout: row = quad*4+r, col = t*16+t16) ----
        float al[4];
        #pragma unroll
        for (int r = 0; r < 4; ++r) {
            float mx = fmaxf(fmaxf(sc[0][r], sc[1][r]), fmaxf(sc[2][r], sc[3][r]));
            #pragma unroll
            for (int off = 8; off > 0; off >>= 1)
                mx = fmaxf(mx, __shfl_xor(mx, off, 16));
            const float mnew = fmaxf(m_i[r], mx);
            al[r] = __expf(m_i[r] - mnew);
            float rs = 0.f;
            #pragma unroll
            for (int t = 0; t < 4; ++t) {
                float p = __expf(sc[t][r] - mnew);
                sc[t][r] = p;
                rs += p;
            }
            #pragma unroll
            for (int off = 8; off > 0; off >>= 1)
                rs += __shfl_xor(rs, off, 16);
            l_i[r] = l_i[r] * al[r] + rs;
            m_i[r] = mnew;
        }
        // write P (bf16) to LDS in [q][j]; intra-wave rows only (DS in-order)
        #pragma unroll
        for (int r = 0; r < 4; ++r)
            #pragma unroll
            for (int t = 0; t < 4; ++t)
                Ps[q0w + quad * 4 + r][t * 16 + t16] = f2bf(sc[t][r]);
        #pragma unroll
        for (int dt = 0; dt < 4; ++dt)
            #pragma unroll
            for (int r = 0; r < 4; ++r)
                o_acc[dt][r] *= al[r];

        // ---- PV: o += P * V  (hi-only) ----
        #pragma unroll
        for (int ks = 0; ks < 2; ++ks) {
            bf16x8 pa = *(const bf16x8*)&Ps[q0w + t16][ks * 32 + quad * 8];
            #pragma unroll
            for (int dt = 0; dt < 4; ++dt) {
                bf16x8 vb = *(const bf16x8*)&Vt[dt * 16 + t16][ks * 32 + quad * 8];
                o_acc[dt] = __builtin_amdgcn_mfma_f32_16x16x32_bf16(pa, vb, o_acc[dt], 0, 0, 0);
            }
        }
    }

    // ---- epilogue: normalize, write O [B,S,E]; save m,l ----
    #pragma unroll
    for (int r = 0; r < 4; ++r) {
        const int row = q0 + q0w + quad * 4 + r;
        const float inv = 1.0f / l_i[r];
        #pragma unroll
        for (int dt = 0; dt < 4; ++dt)
            O[((size_t)(b * TS) + row) * TE + h * TD + dt * 16 + t16] = o_acc[dt][r] * inv;
        if (t16 == 0) {
            Ms[(size_t)(b * TH + h) * TS + row] = m_i[r];
            Ls[(size_t)(b * TH + h) * TS + row] = l_i[r];
        }
    }
}

// ----------------------------------------------------------------------------
// attn_avg (fp32, unchanged R0)
// ----------------------------------------------------------------------------
__global__ __launch_bounds__(256, 2)
void attn_avg_k(const float* __restrict__ Q, const float* __restrict__ Kg,
                const float* __restrict__ Ms, const float* __restrict__ Ls,
                float* __restrict__ AV)
{
    __shared__ float Qt[64][132];
    __shared__ float Kt[64][132];
    const int tid = threadIdx.x, tx = tid & 15, ty = tid >> 4;
    const int j0 = blockIdx.x * 128;
    const int q0 = blockIdx.y * 128;
    const int b = blockIdx.z;

    float acc[8][8];
    #pragma unroll
    for (int i = 0; i < 8; ++i)
        #pragma unroll
        for (int j = 0; j < 8; ++j) acc[i][j] = 0.f;

    for (int h = 0; h < TH; ++h) {
        __syncthreads();
        const size_t hoff = (size_t)(b * TH + h) * TS * TD;
        #pragma unroll
        for (int i = 0; i < 8; ++i) {
            const int f = tid + 256 * i;
            const int row = f >> 4;
            const int dq = (f & 15) * 4;
            float4 qv = *(const float4*)(Q + hoff + (size_t)(q0 + row) * TD + dq);
            Qt[dq + 0][row] = qv.x * 0.125f;
            Qt[dq + 1][row] = qv.y * 0.125f;
            Qt[dq + 2][row] = qv.z * 0.125f;
            Qt[dq + 3][row] = qv.w * 0.125f;
            float4 kv = *(const float4*)(Kg + hoff + (size_t)(j0 + row) * TD + dq);
            Kt[dq + 0][row] = kv.x; Kt[dq + 1][row] = kv.y;
            Kt[dq + 2][row] = kv.z; Kt[dq + 3][row] = kv.w;
        }
        __syncthreads();

        float sc[8][8];
        #pragma unroll
        for (int i = 0; i < 8; ++i)
            #pragma unroll
            for (int j = 0; j < 8; ++j) sc[i][j] = 0.f;

        #pragma unroll 8
        for (int kk = 0; kk < 64; ++kk) {
            float4 a0 = *(const float4*)&Qt[kk][4 * ty];
            float4 a1 = *(const float4*)&Qt[kk][64 + 4 * ty];
            float4 b0 = *(const float4*)&Kt[kk][4 * tx];
            float4 b1 = *(const float4*)&Kt[kk][64 + 4 * tx];
            float a[8]  = {a0.x, a0.y, a0.z, a0.w, a1.x, a1.y, a1.z, a1.w};
            float bb[8] = {b0.x, b0.y, b0.z, b0.w, b1.x, b1.y, b1.z, b1.w};
            #pragma unroll
            for (int i = 0; i < 8; ++i)
                #pragma unroll
                for (int j = 0; j < 8; ++j)
                    sc[i][j] = fmaf(a[i], bb[j], sc[i][j]);
        }

        #pragma unroll
        for (int i = 0; i < 8; ++i) {
            const int r = q0 + ((i < 4) ? (4 * ty + i) : (64 + 4 * ty + i - 4));
            const float mm = Ms[(size_t)(b * TH + h) * TS + r];
            const float il = 1.0f / Ls[(size_t)(b * TH + h) * TS + r];
            #pragma unroll
            for (int j = 0; j < 8; ++j)
                acc[i][j] += __expf(sc[i][j] - mm) * il;
        }
    }

    const float inv_h = 1.0f / (float)TH;
    #pragma unroll
    for (int i = 0; i < 8; ++i) {
        const int r = q0 + ((i < 4) ? (4 * ty + i) : (64 + 4 * ty + i - 4));
        #pragma unroll
        for (int jg = 0; jg < 2; ++jg) {
            const int c = j0 + jg * 64 + 4 * tx;
            float4 v = make_float4(acc[i][jg * 4 + 0] * inv_h, acc[i][jg * 4 + 1] * inv_h,
                                   acc[i][jg * 4 + 2] * inv_h, acc[i][jg * 4 + 3] * inv_h);
            *(float4*)(AV + ((size_t)b * TS + r) * TS + c) = v;
        }
    }
}

// ----------------------------------------------------------------------------
extern "C" void kernel_launch(void* const* d_in, const int* in_sizes, int n_in,
                              void* d_out, int out_size, void* d_ws, size_t ws_size,
                              hipStream_t stream)
{
    const float* query = (const float*)d_in[0];
    const float* key   = (const float*)d_in[1];
    const float* value = (const float*)d_in[2];
    const float* Wq = (const float*)d_in[3];
    const float* bq = (const float*)d_in[4];
    const float* Wk = (const float*)d_in[5];
    const float* bk = (const float*)d_in[6];
    const float* Wv = (const float*)d_in[7];
    const float* bv = (const float*)d_in[8];
    const float* Wo = (const float*)d_in[9];
    const float* bo = (const float*)d_in[10];

    float* ws  = (float*)d_ws;
    float* Qr  = ws + WS_Q;
    float* Kr  = ws + WS_K;
    float* Msf = ws + WS_M;
    float* Lsf = ws + WS_L;
    float* tab = ws + WS_TAB;

    float* out  = (float*)d_out;
    float* attn = out + (size_t)TB * TS * TE;
    float* Vr = attn;
    float* Ow = attn + (size_t)TB * TS * TE;

    dim3 blk(256);
    dim3 gproj(TE / 128, TM_ / 128);

    gemm_nt<1><<<gproj, blk, 0, stream>>>(query, Wq, bq, Qr);
    gemm_nt<1><<<gproj, blk, 0, stream>>>(key,   Wk, bk, Kr);
    gemm_nt<1><<<gproj, blk, 0, stream>>>(value, Wv, bv, Vr);
    rope_table<<<dim3(256), blk, 0, stream>>>(tab);
    rope_apply<<<dim3(32768), blk, 0, stream>>>(Qr, Kr, tab);
    attn_flash<<<dim3(TS / 64, TH, TB), blk, 0, stream>>>(Qr, Kr, Vr, Ow, Msf, Lsf);
    gemm_nt<0><<<gproj, blk, 0, stream>>>(Ow, Wo, bo, out);
    attn_avg_k<<<dim3(TS / 128, TS / 128, TB), blk, 0, stream>>>(Qr, Kr, Msf, Lsf, attn);
}

// Round 3
// 1493.484 us; speedup vs baseline: 1.6672x; 1.2391x over previous
//
#include <hip/hip_runtime.h>
#include <math.h>

// Problem constants
#define TB 4
#define TS 2048
#define TE 1024
#define TH 16
#define TD 64
#define TM_ (TB*TS)   // 8192 rows

// Workspace float offsets
#define WS_Q   0
#define WS_K   8388608
#define WS_M   16777216
#define WS_L   16908288
#define WS_TAB 17039360

typedef __attribute__((ext_vector_type(8))) short bf16x8;  // 8 bf16 = 4 VGPRs
typedef __attribute__((ext_vector_type(4))) float f32x4;

static __device__ inline short f2bf(float x) {
    union { float f; unsigned u; } v; v.f = x;
    unsigned r = v.u + 0x7fff + ((v.u >> 16) & 1);   // RNE
    return (short)(r >> 16);
}
static __device__ inline unsigned fbits(float x) {
    union { float f; unsigned u; } v; v.f = x; return v.u;
}

// ----------------------------------------------------------------------------
// GEMM: C[m,n] = sum_k X[m,k] * W[n,k] + bias[n]  (fp32 VALU, unchanged R0)
// ----------------------------------------------------------------------------
template<int MODE>
__global__ __launch_bounds__(256, 2)
void gemm_nt(const float* __restrict__ X, const float* __restrict__ W,
             const float* __restrict__ bias, float* __restrict__ out)
{
    __shared__ float As[16][132];
    __shared__ float Bs[16][132];
    const int tid = threadIdx.x;
    const int tx = tid & 15, ty = tid >> 4;
    const int m0 = blockIdx.y * 128;
    const int n0 = blockIdx.x * 128;
    const int K = TE, N = TE;

    float acc[8][8];
    #pragma unroll
    for (int i = 0; i < 8; ++i)
        #pragma unroll
        for (int j = 0; j < 8; ++j) acc[i][j] = 0.f;

    for (int kt = 0; kt < K; kt += 16) {
        #pragma unroll
        for (int i = 0; i < 2; ++i) {
            const int f = tid + 256 * i;
            const int row = f >> 2;
            const int kq = (f & 3) * 4;
            float4 av = *(const float4*)(X + (size_t)(m0 + row) * K + kt + kq);
            As[kq + 0][row] = av.x; As[kq + 1][row] = av.y;
            As[kq + 2][row] = av.z; As[kq + 3][row] = av.w;
            float4 bv = *(const float4*)(W + (size_t)(n0 + row) * K + kt + kq);
            Bs[kq + 0][row] = bv.x; Bs[kq + 1][row] = bv.y;
            Bs[kq + 2][row] = bv.z; Bs[kq + 3][row] = bv.w;
        }
        __syncthreads();
        #pragma unroll
        for (int kk = 0; kk < 16; ++kk) {
            float4 a0 = *(const float4*)&As[kk][4 * ty];
            float4 a1 = *(const float4*)&As[kk][64 + 4 * ty];
            float4 b0 = *(const float4*)&Bs[kk][4 * tx];
            float4 b1 = *(const float4*)&Bs[kk][64 + 4 * tx];
            float a[8]  = {a0.x, a0.y, a0.z, a0.w, a1.x, a1.y, a1.z, a1.w};
            float bb[8] = {b0.x, b0.y, b0.z, b0.w, b1.x, b1.y, b1.z, b1.w};
            #pragma unroll
            for (int i = 0; i < 8; ++i)
                #pragma unroll
                for (int j = 0; j < 8; ++j)
                    acc[i][j] = fmaf(a[i], bb[j], acc[i][j]);
        }
        __syncthreads();
    }

    #pragma unroll
    for (int i = 0; i < 8; ++i) {
        const int r = m0 + ((i < 4) ? (4 * ty + i) : (64 + 4 * ty + i - 4));
        #pragma unroll
        for (int jg = 0; jg < 2; ++jg) {
            const int cl = jg * 64 + 4 * tx;
            const int n = n0 + cl;
            float4 bv = *(const float4*)(bias + n);
            float4 v;
            v.x = acc[i][jg * 4 + 0] + bv.x;
            v.y = acc[i][jg * 4 + 1] + bv.y;
            v.z = acc[i][jg * 4 + 2] + bv.z;
            v.w = acc[i][jg * 4 + 3] + bv.w;
            if (MODE == 0) {
                *(float4*)(out + (size_t)r * N + n) = v;
            } else {
                const int bb_ = r >> 11, s = r & 2047;
                const int h = n >> 6, d = n & 63;
                *(float4*)(out + ((size_t)(bb_ * TH + h) * TS + s) * TD + d) = v;
            }
        }
    }
}

// ----------------------------------------------------------------------------
// RoPE (unchanged)
// ----------------------------------------------------------------------------
__global__ void rope_table(float* __restrict__ tab)
{
    const int idx = blockIdx.x * 256 + threadIdx.x;
    const int d = idx & 31, s = idx >> 5;
    const float e = (float)(2 * d) / 64.0f;
    const float inv = 1.0f / powf(10000.0f, e);
    const float a = (float)s * inv;
    tab[2 * idx + 0] = cosf(a);
    tab[2 * idx + 1] = sinf(a);
}

__global__ void rope_apply(float* __restrict__ Q, float* __restrict__ Kv,
                           const float* __restrict__ tab)
{
    const int idx = blockIdx.x * 256 + threadIdx.x;
    const int half = TB * TH * TS * 32;
    float* P = (idx < half) ? Q : Kv;
    const int u = idx & (half - 1);
    const int d = u & 31;
    const int s = (u >> 5) & 2047;
    const int bh = u >> 16;
    const size_t base = (size_t)bh * (TS * TD) + (size_t)s * TD;
    const float c  = tab[2 * (s * 32 + d) + 0];
    const float sn = tab[2 * (s * 32 + d) + 1];
    const float x0 = P[base + d], x1 = P[base + d + 32];
    P[base + d]      = x0 * c - x1 * sn;
    P[base + d + 32] = x1 * c + x0 * sn;
}

// ----------------------------------------------------------------------------
// Flash attention with MFMA (unchanged R1).
// ----------------------------------------------------------------------------
__global__ __launch_bounds__(256, 2)
void attn_flash(const float* __restrict__ Q, const float* __restrict__ Kg,
                const float* __restrict__ V, float* __restrict__ O,
                float* __restrict__ Ms, float* __restrict__ Ls)
{
    __shared__ short Qh[64][72], Ql[64][72];
    __shared__ short Kh[64][72], Kl[64][72];
    __shared__ short Vt[64][72];            // V^T: [d][j]
    __shared__ short Ps[64][72];            // P:   [q][j]

    const int tid  = threadIdx.x;
    const int lane = tid & 63;
    const int wv   = tid >> 6;
    const int t16  = lane & 15;
    const int quad = lane >> 4;
    const int q0w  = wv * 16;

    const int q0 = blockIdx.x * 64;
    const int h = blockIdx.y, b = blockIdx.z;
    const size_t hoff = (size_t)(b * TH + h) * TS * TD;
    const float* Qg = Q + hoff;
    const float* Kh_g = Kg + hoff;
    const float* Vg = V + hoff;

    #pragma unroll
    for (int i = 0; i < 4; ++i) {
        const int f = tid + 256 * i;
        const int row = f >> 4;
        const int dq = (f & 15) * 4;
        float4 qv = *(const float4*)(Qg + (size_t)(q0 + row) * TD + dq);
        float x[4] = {qv.x * 0.125f, qv.y * 0.125f, qv.z * 0.125f, qv.w * 0.125f};
        short hs[4], ls[4];
        #pragma unroll
        for (int c = 0; c < 4; ++c) {
            hs[c] = f2bf(x[c]);
            union { unsigned u; float f; } bk; bk.u = ((unsigned)(unsigned short)hs[c]) << 16;
            ls[c] = f2bf(x[c] - bk.f);
        }
        *(short4*)&Qh[row][dq] = make_short4(hs[0], hs[1], hs[2], hs[3]);
        *(short4*)&Ql[row][dq] = make_short4(ls[0], ls[1], ls[2], ls[3]);
    }
    __syncthreads();

    bf16x8 qfh[2], qfl[2];
    #pragma unroll
    for (int ks = 0; ks < 2; ++ks) {
        qfh[ks] = *(const bf16x8*)&Qh[q0w + t16][ks * 32 + quad * 8];
        qfl[ks] = *(const bf16x8*)&Ql[q0w + t16][ks * 32 + quad * 8];
    }

    float m_i[4], l_i[4];
    f32x4 o_acc[4];
    #pragma unroll
    for (int r = 0; r < 4; ++r) { m_i[r] = -1e30f; l_i[r] = 0.f; }
    #pragma unroll
    for (int dt = 0; dt < 4; ++dt) o_acc[dt] = (f32x4){0.f, 0.f, 0.f, 0.f};

    for (int j0 = 0; j0 < TS; j0 += 64) {
        __syncthreads();
        #pragma unroll
        for (int i = 0; i < 4; ++i) {
            const int f = tid + 256 * i;
            const int row = f >> 4;
            const int dq = (f & 15) * 4;
            float4 kv = *(const float4*)(Kh_g + (size_t)(j0 + row) * TD + dq);
            float x[4] = {kv.x, kv.y, kv.z, kv.w};
            short hs[4], ls[4];
            #pragma unroll
            for (int c = 0; c < 4; ++c) {
                hs[c] = f2bf(x[c]);
                union { unsigned u; float f; } bk; bk.u = ((unsigned)(unsigned short)hs[c]) << 16;
                ls[c] = f2bf(x[c] - bk.f);
            }
            *(short4*)&Kh[row][dq] = make_short4(hs[0], hs[1], hs[2], hs[3]);
            *(short4*)&Kl[row][dq] = make_short4(ls[0], ls[1], ls[2], ls[3]);
        }
        #pragma unroll
        for (int i = 0; i < 4; ++i) {
            const int f = tid + 256 * i;
            const int t_ = f & 15;
            const int qd = (f >> 4) & 3;
            const int s_ = f >> 6;
            const int vrow = t_ + 16 * (s_ & 3);
            const int vq = qd + 4 * (s_ >> 2);
            float4 vv = *(const float4*)(Vg + (size_t)(j0 + vrow) * TD + vq * 4);
            Vt[vq * 4 + 0][vrow] = f2bf(vv.x);
            Vt[vq * 4 + 1][vrow] = f2bf(vv.y);
            Vt[vq * 4 + 2][vrow] = f2bf(vv.z);
            Vt[vq * 4 + 3][vrow] = f2bf(vv.w);
        }
        __syncthreads();

        f32x4 sc[4];
        #pragma unroll
        for (int t = 0; t < 4; ++t) sc[t] = (f32x4){0.f, 0.f, 0.f, 0.f};
        #pragma unroll
        for (int t = 0; t < 4; ++t) {
            #pragma unroll
            for (int ks = 0; ks < 2; ++ks) {
                bf16x8 kf_h = *(const bf16x8*)&Kh[t * 16 + t16][ks * 32 + quad * 8];
                bf16x8 kf_l = *(const bf16x8*)&Kl[t * 16 + t16][ks * 32 + quad * 8];
                sc[t] = __builtin_amdgcn_mfma_f32_16x16x32_bf16(qfh[ks], kf_h, sc[t], 0, 0, 0);
                sc[t] = __builtin_amdgcn_mfma_f32_16x16x32_bf16(qfh[ks], kf_l, sc[t], 0, 0, 0);
                sc[t] = __builtin_amdgcn_mfma_f32_16x16x32_bf16(qfl[ks], kf_h, sc[t], 0, 0, 0);
            }
        }

        float al[4];
        #pragma unroll
        for (int r = 0; r < 4; ++r) {
            float mx = fmaxf(fmaxf(sc[0][r], sc[1][r]), fmaxf(sc[2][r], sc[3][r]));
            #pragma unroll
            for (int off = 8; off > 0; off >>= 1)
                mx = fmaxf(mx, __shfl_xor(mx, off, 16));
            const float mnew = fmaxf(m_i[r], mx);
            al[r] = __expf(m_i[r] - mnew);
            float rs = 0.f;
            #pragma unroll
            for (int t = 0; t < 4; ++t) {
                float p = __expf(sc[t][r] - mnew);
                sc[t][r] = p;
                rs += p;
            }
            #pragma unroll
            for (int off = 8; off > 0; off >>= 1)
                rs += __shfl_xor(rs, off, 16);
            l_i[r] = l_i[r] * al[r] + rs;
            m_i[r] = mnew;
        }
        #pragma unroll
        for (int r = 0; r < 4; ++r)
            #pragma unroll
            for (int t = 0; t < 4; ++t)
                Ps[q0w + quad * 4 + r][t * 16 + t16] = f2bf(sc[t][r]);
        #pragma unroll
        for (int dt = 0; dt < 4; ++dt)
            #pragma unroll
            for (int r = 0; r < 4; ++r)
                o_acc[dt][r] *= al[r];

        #pragma unroll
        for (int ks = 0; ks < 2; ++ks) {
            bf16x8 pa = *(const bf16x8*)&Ps[q0w + t16][ks * 32 + quad * 8];
            #pragma unroll
            for (int dt = 0; dt < 4; ++dt) {
                bf16x8 vb = *(const bf16x8*)&Vt[dt * 16 + t16][ks * 32 + quad * 8];
                o_acc[dt] = __builtin_amdgcn_mfma_f32_16x16x32_bf16(pa, vb, o_acc[dt], 0, 0, 0);
            }
        }
    }

    #pragma unroll
    for (int r = 0; r < 4; ++r) {
        const int row = q0 + q0w + quad * 4 + r;
        const float inv = 1.0f / l_i[r];
        #pragma unroll
        for (int dt = 0; dt < 4; ++dt)
            O[((size_t)(b * TS) + row) * TE + h * TD + dt * 16 + t16] = o_acc[dt][r] * inv;
        if (t16 == 0) {
            Ms[(size_t)(b * TH + h) * TS + row] = m_i[r];
            Ls[(size_t)(b * TH + h) * TS + row] = l_i[r];
        }
    }
}

// ----------------------------------------------------------------------------
// attn_avg with MFMA: per (b, 128q, 128j) block, loop 16 heads, recompute
// scores with hi-only truncated bf16 (error ~5e-5 in p, analyzed), apply
// p = exp2(s*log2e - m*log2e) * (1/l) using pre-staged stats, accumulate.
// Waves in 2x2 layout; each wave owns a 64x64 quadrant (4x4 MFMA tiles).
// ----------------------------------------------------------------------------
__global__ __launch_bounds__(256, 2)
void attn_avg_k(const float* __restrict__ Q, const float* __restrict__ Kg,
                const float* __restrict__ Ms, const float* __restrict__ Ls,
                float* __restrict__ AV)
{
    __shared__ short Qt[128][72];        // [q][d] bf16, Q pre-scaled by 0.125*log2e
    __shared__ short Kt[128][72];        // [j][d] bf16
    __shared__ float ML[TH][128][2];     // [h][row][{m*log2e, 1/l}]

    const int tid  = threadIdx.x;
    const int lane = tid & 63;
    const int wv   = tid >> 6;
    const int t16  = lane & 15;
    const int quad = lane >> 4;
    const int wq = (wv >> 1) * 64;       // wave's q offset within tile
    const int wj = (wv & 1) * 64;        // wave's j offset within tile

    const int j0 = blockIdx.x * 128;
    const int q0 = blockIdx.y * 128;
    const int b  = blockIdx.z;

    // ---- stage m*log2e and 1/l for all heads, rows q0..q0+127 ----
    #pragma unroll
    for (int i = 0; i < 8; ++i) {
        const int u = tid + 256 * i;          // 2048
        const int h = u >> 7, r = u & 127;
        const size_t off = (size_t)(b * TH + h) * TS + q0 + r;
        ML[h][r][0] = Ms[off] * 1.44269504f;
        ML[h][r][1] = 1.0f / Ls[off];
    }

    f32x4 acc[4][4];
    #pragma unroll
    for (int mt = 0; mt < 4; ++mt)
        #pragma unroll
        for (int nt = 0; nt < 4; ++nt) acc[mt][nt] = (f32x4){0.f, 0.f, 0.f, 0.f};

    const float qscale = 0.125f * 1.44269504f;

    for (int h = 0; h < TH; ++h) {
        __syncthreads();   // prev head's frag reads done (iter0: ML visible after next sync)
        const size_t hoff = (size_t)(b * TH + h) * TS * TD;
        // ---- stage Q (scaled) and K tiles, truncated bf16 via v_perm pack ----
        #pragma unroll
        for (int i = 0; i < 8; ++i) {
            const int f = tid + 256 * i;      // 2048 float4 per matrix
            const int row = f >> 4;
            const int dq = (f & 15) * 4;
            float4 qv = *(const float4*)(Q + hoff + (size_t)(q0 + row) * TD + dq);
            unsigned q01 = __builtin_amdgcn_perm(fbits(qv.y * qscale), fbits(qv.x * qscale), 0x07060302u);
            unsigned q23 = __builtin_amdgcn_perm(fbits(qv.w * qscale), fbits(qv.z * qscale), 0x07060302u);
            uint2 qp = make_uint2(q01, q23);
            *(uint2*)&Qt[row][dq] = qp;
            float4 kv = *(const float4*)(Kg + hoff + (size_t)(j0 + row) * TD + dq);
            unsigned k01 = __builtin_amdgcn_perm(fbits(kv.y), fbits(kv.x), 0x07060302u);
            unsigned k23 = __builtin_amdgcn_perm(fbits(kv.w), fbits(kv.z), 0x07060302u);
            uint2 kp = make_uint2(k01, k23);
            *(uint2*)&Kt[row][dq] = kp;
        }
        __syncthreads();

        // ---- scores: 4x4 MFMA tiles x 2 ksteps ----
        f32x4 sc[4][4];
        #pragma unroll
        for (int mt = 0; mt < 4; ++mt)
            #pragma unroll
            for (int nt = 0; nt < 4; ++nt) sc[mt][nt] = (f32x4){0.f, 0.f, 0.f, 0.f};
        #pragma unroll
        for (int ks = 0; ks < 2; ++ks) {
            bf16x8 af[4], bf[4];
            #pragma unroll
            for (int mt = 0; mt < 4; ++mt)
                af[mt] = *(const bf16x8*)&Qt[wq + mt * 16 + t16][ks * 32 + quad * 8];
            #pragma unroll
            for (int nt = 0; nt < 4; ++nt)
                bf[nt] = *(const bf16x8*)&Kt[wj + nt * 16 + t16][ks * 32 + quad * 8];
            #pragma unroll
            for (int mt = 0; mt < 4; ++mt)
                #pragma unroll
                for (int nt = 0; nt < 4; ++nt)
                    sc[mt][nt] = __builtin_amdgcn_mfma_f32_16x16x32_bf16(af[mt], bf[nt], sc[mt][nt], 0, 0, 0);
        }

        // ---- p = exp2(s' - m') * invl, accumulate over heads ----
        #pragma unroll
        for (int mt = 0; mt < 4; ++mt) {
            const int rl = wq + mt * 16 + quad * 4;     // C layout row base
            float4 ml01 = *(const float4*)&ML[h][rl][0];      // rows r=0,1
            float4 ml23 = *(const float4*)&ML[h][rl + 2][0];  // rows r=2,3
            const float mv[4] = {ml01.x, ml01.z, ml23.x, ml23.z};
            const float lv[4] = {ml01.y, ml01.w, ml23.y, ml23.w};
            #pragma unroll
            for (int nt = 0; nt < 4; ++nt)
                #pragma unroll
                for (int r = 0; r < 4; ++r)
                    acc[mt][nt][r] = fmaf(__builtin_amdgcn_exp2f(sc[mt][nt][r] - mv[r]), lv[r], acc[mt][nt][r]);
        }
    }

    // ---- write mean over heads (C layout: row=quad*4+r, col=t16) ----
    const float inv_h = 1.0f / (float)TH;
    #pragma unroll
    for (int mt = 0; mt < 4; ++mt) {
        #pragma unroll
        for (int r = 0; r < 4; ++r) {
            const int row = q0 + wq + mt * 16 + quad * 4 + r;
            #pragma unroll
            for (int nt = 0; nt < 4; ++nt) {
                const int col = j0 + wj + nt * 16 + t16;
                AV[((size_t)b * TS + row) * TS + col] = acc[mt][nt][r] * inv_h;
            }
        }
    }
}

// ----------------------------------------------------------------------------
extern "C" void kernel_launch(void* const* d_in, const int* in_sizes, int n_in,
                              void* d_out, int out_size, void* d_ws, size_t ws_size,
                              hipStream_t stream)
{
    const float* query = (const float*)d_in[0];
    const float* key   = (const float*)d_in[1];
    const float* value = (const float*)d_in[2];
    const float* Wq = (const float*)d_in[3];
    const float* bq = (const float*)d_in[4];
    const float* Wk = (const float*)d_in[5];
    const float* bk = (const float*)d_in[6];
    const float* Wv = (const float*)d_in[7];
    const float* bv = (const float*)d_in[8];
    const float* Wo = (const float*)d_in[9];
    const float* bo = (const float*)d_in[10];

    float* ws  = (float*)d_ws;
    float* Qr  = ws + WS_Q;
    float* Kr  = ws + WS_K;
    float* Msf = ws + WS_M;
    float* Lsf = ws + WS_L;
    float* tab = ws + WS_TAB;

    float* out  = (float*)d_out;
    float* attn = out + (size_t)TB * TS * TE;
    float* Vr = attn;
    float* Ow = attn + (size_t)TB * TS * TE;

    dim3 blk(256);
    dim3 gproj(TE / 128, TM_ / 128);

    gemm_nt<1><<<gproj, blk, 0, stream>>>(query, Wq, bq, Qr);
    gemm_nt<1><<<gproj, blk, 0, stream>>>(key,   Wk, bk, Kr);
    gemm_nt<1><<<gproj, blk, 0, stream>>>(value, Wv, bv, Vr);
    rope_table<<<dim3(256), blk, 0, stream>>>(tab);
    rope_apply<<<dim3(32768), blk, 0, stream>>>(Qr, Kr, tab);
    attn_flash<<<dim3(TS / 64, TH, TB), blk, 0, stream>>>(Qr, Kr, Vr, Ow, Msf, Lsf);
    gemm_nt<0><<<gproj, blk, 0, stream>>>(Ow, Wo, bo, out);
    attn_avg_k<<<dim3(TS / 128, TS / 128, TB), blk, 0, stream>>>(Qr, Kr, Msf, Lsf, attn);
}

// Round 4
// 1276.987 us; speedup vs baseline: 1.9498x; 1.1695x over previous
//
#include <hip/hip_runtime.h>
#include <math.h>

// Problem constants
#define TB 4
#define TS 2048
#define TE 1024
#define TH 16
#define TD 64
#define TM_ (TB*TS)   // 8192 rows

// Workspace float offsets
#define WS_Q   0
#define WS_K   8388608
#define WS_L   16777216
#define WS_TAB 16908288

typedef __attribute__((ext_vector_type(8))) short bf16x8;  // 8 bf16 = 4 VGPRs
typedef __attribute__((ext_vector_type(4))) float f32x4;

static __device__ inline unsigned fbits(float x) {
    union { float f; unsigned u; } v; v.f = x; return v.u;
}
static __device__ inline float bits2f(unsigned u) {
    union { unsigned u; float f; } v; v.u = u; return v.f;
}
// pack [bf16(a), bf16(b)] (round-half-up) into one dword, a in low half
static __device__ inline unsigned pack_rhu(float a, float b) {
    return __builtin_amdgcn_perm(fbits(b) + 0x8000u, fbits(a) + 0x8000u, 0x07060302u);
}
// hi/lo split of (x0,x1): hp = packed hi bf16s, lp = packed lo bf16s
static __device__ inline void split2(float x0, float x1, unsigned& hp, unsigned& lp) {
    unsigned u0 = fbits(x0) + 0x8000u, u1 = fbits(x1) + 0x8000u;
    hp = __builtin_amdgcn_perm(u1, u0, 0x07060302u);
    float h0 = bits2f(u0 & 0xffff0000u);
    float h1 = bits2f(u1 & 0xffff0000u);
    lp = pack_rhu(x0 - h0, x1 - h1);
}

// ----------------------------------------------------------------------------
// GEMM: C[m,n] = sum_k X[m,k] * W[n,k] + bias[n]  (fp32 VALU)
// MODE 0: fp32 out[m*N+n];  MODE 1: fp32 [B,H,S,D];  MODE 2: bf16 V^T [B,H,D,S]
// ----------------------------------------------------------------------------
template<int MODE>
__global__ __launch_bounds__(256, 2)
void gemm_nt(const float* __restrict__ X, const float* __restrict__ W,
             const float* __restrict__ bias, float* __restrict__ out)
{
    __shared__ float As[16][132];
    __shared__ float Bs[16][132];
    const int tid = threadIdx.x;
    const int tx = tid & 15, ty = tid >> 4;
    const int m0 = blockIdx.y * 128;
    const int n0 = blockIdx.x * 128;
    const int K = TE, N = TE;

    float acc[8][8];
    #pragma unroll
    for (int i = 0; i < 8; ++i)
        #pragma unroll
        for (int j = 0; j < 8; ++j) acc[i][j] = 0.f;

    for (int kt = 0; kt < K; kt += 16) {
        #pragma unroll
        for (int i = 0; i < 2; ++i) {
            const int f = tid + 256 * i;
            const int row = f >> 2;
            const int kq = (f & 3) * 4;
            float4 av = *(const float4*)(X + (size_t)(m0 + row) * K + kt + kq);
            As[kq + 0][row] = av.x; As[kq + 1][row] = av.y;
            As[kq + 2][row] = av.z; As[kq + 3][row] = av.w;
            float4 bv = *(const float4*)(W + (size_t)(n0 + row) * K + kt + kq);
            Bs[kq + 0][row] = bv.x; Bs[kq + 1][row] = bv.y;
            Bs[kq + 2][row] = bv.z; Bs[kq + 3][row] = bv.w;
        }
        __syncthreads();
        #pragma unroll
        for (int kk = 0; kk < 16; ++kk) {
            float4 a0 = *(const float4*)&As[kk][4 * ty];
            float4 a1 = *(const float4*)&As[kk][64 + 4 * ty];
            float4 b0 = *(const float4*)&Bs[kk][4 * tx];
            float4 b1 = *(const float4*)&Bs[kk][64 + 4 * tx];
            float a[8]  = {a0.x, a0.y, a0.z, a0.w, a1.x, a1.y, a1.z, a1.w};
            float bb[8] = {b0.x, b0.y, b0.z, b0.w, b1.x, b1.y, b1.z, b1.w};
            #pragma unroll
            for (int i = 0; i < 8; ++i)
                #pragma unroll
                for (int j = 0; j < 8; ++j)
                    acc[i][j] = fmaf(a[i], bb[j], acc[i][j]);
        }
        __syncthreads();
    }

    if (MODE == 2) {
        // write bf16 V^T [B,H,D,S]; 4 s-consecutive rows packed per 8B store
        short* o16 = (short*)out;
        const int b = m0 >> 11;
        const int sA = (m0 & 2047) + 4 * ty;       // rows i=0..3
        const int sB = sA + 64;                    // rows i=4..7
        #pragma unroll
        for (int jg = 0; jg < 2; ++jg) {
            #pragma unroll
            for (int j = 0; j < 4; ++j) {
                const int n = n0 + jg * 64 + 4 * tx + j;
                const int h = n >> 6, d = n & 63;
                const float bv = bias[n];
                const int aj = jg * 4 + j;
                size_t base = ((size_t)(b * TH + h) * TD + d) * TS;
                uint2 pA = make_uint2(pack_rhu(acc[0][aj] + bv, acc[1][aj] + bv),
                                      pack_rhu(acc[2][aj] + bv, acc[3][aj] + bv));
                *(uint2*)(o16 + base + sA) = pA;
                uint2 pB = make_uint2(pack_rhu(acc[4][aj] + bv, acc[5][aj] + bv),
                                      pack_rhu(acc[6][aj] + bv, acc[7][aj] + bv));
                *(uint2*)(o16 + base + sB) = pB;
            }
        }
        return;
    }

    #pragma unroll
    for (int i = 0; i < 8; ++i) {
        const int r = m0 + ((i < 4) ? (4 * ty + i) : (64 + 4 * ty + i - 4));
        #pragma unroll
        for (int jg = 0; jg < 2; ++jg) {
            const int cl = jg * 64 + 4 * tx;
            const int n = n0 + cl;
            float4 bv = *(const float4*)(bias + n);
            float4 v;
            v.x = acc[i][jg * 4 + 0] + bv.x;
            v.y = acc[i][jg * 4 + 1] + bv.y;
            v.z = acc[i][jg * 4 + 2] + bv.z;
            v.w = acc[i][jg * 4 + 3] + bv.w;
            if (MODE == 0) {
                *(float4*)(out + (size_t)r * N + n) = v;
            } else {
                const int bb_ = r >> 11, s = r & 2047;
                const int h = n >> 6, d = n & 63;
                *(float4*)(out + ((size_t)(bb_ * TH + h) * TS + s) * TD + d) = v;
            }
        }
    }
}

// ----------------------------------------------------------------------------
// RoPE (unchanged)
// ----------------------------------------------------------------------------
__global__ void rope_table(float* __restrict__ tab)
{
    const int idx = blockIdx.x * 256 + threadIdx.x;
    const int d = idx & 31, s = idx >> 5;
    const float e = (float)(2 * d) / 64.0f;
    const float inv = 1.0f / powf(10000.0f, e);
    const float a = (float)s * inv;
    tab[2 * idx + 0] = cosf(a);
    tab[2 * idx + 1] = sinf(a);
}

__global__ void rope_apply(float* __restrict__ Q, float* __restrict__ Kv,
                           const float* __restrict__ tab)
{
    const int idx = blockIdx.x * 256 + threadIdx.x;
    const int half = TB * TH * TS * 32;
    float* P = (idx < half) ? Q : Kv;
    const int u = idx & (half - 1);
    const int d = u & 31;
    const int s = (u >> 5) & 2047;
    const int bh = u >> 16;
    const size_t base = (size_t)bh * (TS * TD) + (size_t)s * TD;
    const float c  = tab[2 * (s * 32 + d) + 0];
    const float sn = tab[2 * (s * 32 + d) + 1];
    const float x0 = P[base + d], x1 = P[base + d + 32];
    P[base + d]      = x0 * c - x1 * sn;
    P[base + d + 32] = x1 * c + x0 * sn;
}

// ----------------------------------------------------------------------------
// Flash attention, restructured (R3):
//  - 128-row q-tile, 512 threads (8 waves), LDS 46 KB (<=3 blocks/CU)
//  - fixed m=0 softmax (scores bounded): no max tracking, no rescale,
//    per-row l accumulated in registers, one shuffle-reduce at the end
//  - Q frags loaded directly from global (fp32 -> split-bf16 in regs)
//  - K staged from fp32 with cheap round-half-up hi/lo split
//  - V^T staged straight from preconverted bf16 global [B,H,D,S]
// ----------------------------------------------------------------------------
__global__ __launch_bounds__(512, 4)
void attn_flash(const float* __restrict__ Q, const float* __restrict__ Kg,
                const short* __restrict__ VT, float* __restrict__ O,
                float* __restrict__ Ls)
{
    __shared__ short Kh[64][72], Kl[64][72];
    __shared__ short Vt[64][72];            // V^T tile: [d][j]
    __shared__ short Ps[128][72];           // P: [q][j]

    const int tid  = threadIdx.x;
    const int lane = tid & 63;
    const int wv   = tid >> 6;        // wave 0..7
    const int t16  = lane & 15;
    const int quad = lane >> 4;
    const int q0w  = wv * 16;         // wave's q-row base within 128-tile

    const int q0 = blockIdx.x * 128;
    const int h = blockIdx.y, b = blockIdx.z;
    const int bh = b * TH + h;
    const size_t hoff = (size_t)bh * TS * TD;
    const float* Kr = Kg + hoff;
    const short* Vth = VT + (size_t)bh * TD * TS;

    // ---- Q fragments straight from global, scaled by 0.125*log2(e), split ----
    const float qsc = 0.125f * 1.44269504f;
    bf16x8 qfh[2], qfl[2];
    {
        const float* qp = Q + hoff + (size_t)(q0 + q0w + t16) * TD;
        #pragma unroll
        for (int ks = 0; ks < 2; ++ks) {
            float4 a = *(const float4*)(qp + ks * 32 + quad * 8);
            float4 c = *(const float4*)(qp + ks * 32 + quad * 8 + 4);
            union { unsigned u[4]; bf16x8 v; } H, L;
            split2(a.x * qsc, a.y * qsc, H.u[0], L.u[0]);
            split2(a.z * qsc, a.w * qsc, H.u[1], L.u[1]);
            split2(c.x * qsc, c.y * qsc, H.u[2], L.u[2]);
            split2(c.z * qsc, c.w * qsc, H.u[3], L.u[3]);
            qfh[ks] = H.v; qfl[ks] = L.v;
        }
    }

    float lsum[4];
    f32x4 o_acc[4];
    #pragma unroll
    for (int r = 0; r < 4; ++r) lsum[r] = 0.f;
    #pragma unroll
    for (int dt = 0; dt < 4; ++dt) o_acc[dt] = (f32x4){0.f, 0.f, 0.f, 0.f};

    // staging indices (512 threads)
    const int krow = tid >> 3;           // 0..63
    const int kcol = (tid & 7) * 8;      // 0..56

    for (int j0 = 0; j0 < TS; j0 += 64) {
        __syncthreads();   // prev iter's Kh/Kl/Vt/Ps reads done
        // ---- stage K tile (fp32 -> hi/lo bf16), 8 elems per thread ----
        {
            const float* kp = Kr + (size_t)(j0 + krow) * TD + kcol;
            float4 a = *(const float4*)kp;
            float4 c = *(const float4*)(kp + 4);
            union { unsigned u[4]; } H, L;
            split2(a.x, a.y, H.u[0], L.u[0]);
            split2(a.z, a.w, H.u[1], L.u[1]);
            split2(c.x, c.y, H.u[2], L.u[2]);
            split2(c.z, c.w, H.u[3], L.u[3]);
            *(uint4*)&Kh[krow][kcol] = make_uint4(H.u[0], H.u[1], H.u[2], H.u[3]);
            *(uint4*)&Kl[krow][kcol] = make_uint4(L.u[0], L.u[1], L.u[2], L.u[3]);
            // ---- stage V^T tile (already bf16), 8 shorts per thread ----
            uint4 vv = *(const uint4*)(Vth + (size_t)krow * TS + j0 + kcol);
            *(uint4*)&Vt[krow][kcol] = vv;
        }
        __syncthreads();

        // ---- scores: 4 j-subtiles x 2 ksteps x 3 split terms ----
        f32x4 sc[4];
        #pragma unroll
        for (int t = 0; t < 4; ++t) sc[t] = (f32x4){0.f, 0.f, 0.f, 0.f};
        #pragma unroll
        for (int t = 0; t < 4; ++t) {
            #pragma unroll
            for (int ks = 0; ks < 2; ++ks) {
                bf16x8 kf_h = *(const bf16x8*)&Kh[t * 16 + t16][ks * 32 + quad * 8];
                bf16x8 kf_l = *(const bf16x8*)&Kl[t * 16 + t16][ks * 32 + quad * 8];
                sc[t] = __builtin_amdgcn_mfma_f32_16x16x32_bf16(qfh[ks], kf_h, sc[t], 0, 0, 0);
                sc[t] = __builtin_amdgcn_mfma_f32_16x16x32_bf16(qfh[ks], kf_l, sc[t], 0, 0, 0);
                sc[t] = __builtin_amdgcn_mfma_f32_16x16x32_bf16(qfl[ks], kf_h, sc[t], 0, 0, 0);
            }
        }

        // ---- p = exp2(s'), accumulate l, write P (bf16) to LDS ----
        #pragma unroll
        for (int t = 0; t < 4; ++t) {
            float p0 = __builtin_amdgcn_exp2f(sc[t][0]);
            float p1 = __builtin_amdgcn_exp2f(sc[t][1]);
            float p2 = __builtin_amdgcn_exp2f(sc[t][2]);
            float p3 = __builtin_amdgcn_exp2f(sc[t][3]);
            lsum[0] += p0; lsum[1] += p1; lsum[2] += p2; lsum[3] += p3;
            const int col = t * 16 + t16;
            Ps[q0w + quad * 4 + 0][col] = (short)(pack_rhu(p0, p0) & 0xffff);
            Ps[q0w + quad * 4 + 1][col] = (short)(pack_rhu(p1, p1) & 0xffff);
            Ps[q0w + quad * 4 + 2][col] = (short)(pack_rhu(p2, p2) & 0xffff);
            Ps[q0w + quad * 4 + 3][col] = (short)(pack_rhu(p3, p3) & 0xffff);
        }

        // ---- PV: o += P * V (intra-wave Ps rows; compiler inserts lgkm waits) ----
        #pragma unroll
        for (int ks = 0; ks < 2; ++ks) {
            bf16x8 pa = *(const bf16x8*)&Ps[q0w + t16][ks * 32 + quad * 8];
            #pragma unroll
            for (int dt = 0; dt < 4; ++dt) {
                bf16x8 vb = *(const bf16x8*)&Vt[dt * 16 + t16][ks * 32 + quad * 8];
                o_acc[dt] = __builtin_amdgcn_mfma_f32_16x16x32_bf16(pa, vb, o_acc[dt], 0, 0, 0);
            }
        }
    }

    // ---- reduce l over the 16 t16 lanes (rows live on fixed quad) ----
    #pragma unroll
    for (int r = 0; r < 4; ++r) {
        #pragma unroll
        for (int off = 1; off < 16; off <<= 1)
            lsum[r] += __shfl_xor(lsum[r], off, 16);
    }

    // ---- epilogue: O[b,s,h*64+d] = o/l; save l ----
    #pragma unroll
    for (int r = 0; r < 4; ++r) {
        const int row = q0 + q0w + quad * 4 + r;
        const float inv = 1.0f / lsum[r];
        #pragma unroll
        for (int dt = 0; dt < 4; ++dt)
            O[((size_t)(b * TS) + row) * TE + h * TD + dt * 16 + t16] = o_acc[dt][r] * inv;
        if (t16 == 0)
            Ls[(size_t)bh * TS + row] = lsum[r];
    }
}

// ----------------------------------------------------------------------------
// attn_avg with MFMA (R2 structure; m=0 softmax -> only 1/l needed)
// ----------------------------------------------------------------------------
__global__ __launch_bounds__(256, 2)
void attn_avg_k(const float* __restrict__ Q, const float* __restrict__ Kg,
                const float* __restrict__ Ls, float* __restrict__ AV)
{
    __shared__ short Qt[128][72];        // [q][d] bf16, Q pre-scaled by 0.125*log2e
    __shared__ short Kt[128][72];        // [j][d] bf16
    __shared__ float ML[TH][128];        // [h][row] = 1/l

    const int tid  = threadIdx.x;
    const int lane = tid & 63;
    const int wv   = tid >> 6;
    const int t16  = lane & 15;
    const int quad = lane >> 4;
    const int wq = (wv >> 1) * 64;
    const int wj = (wv & 1) * 64;

    const int j0 = blockIdx.x * 128;
    const int q0 = blockIdx.y * 128;
    const int b  = blockIdx.z;

    #pragma unroll
    for (int i = 0; i < 8; ++i) {
        const int u = tid + 256 * i;          // 2048
        const int h = u >> 7, r = u & 127;
        ML[h][r] = 1.0f / Ls[(size_t)(b * TH + h) * TS + q0 + r];
    }

    f32x4 acc[4][4];
    #pragma unroll
    for (int mt = 0; mt < 4; ++mt)
        #pragma unroll
        for (int nt = 0; nt < 4; ++nt) acc[mt][nt] = (f32x4){0.f, 0.f, 0.f, 0.f};

    const float qscale = 0.125f * 1.44269504f;

    for (int h = 0; h < TH; ++h) {
        __syncthreads();
        const size_t hoff = (size_t)(b * TH + h) * TS * TD;
        #pragma unroll
        for (int i = 0; i < 8; ++i) {
            const int f = tid + 256 * i;
            const int row = f >> 4;
            const int dq = (f & 15) * 4;
            float4 qv = *(const float4*)(Q + hoff + (size_t)(q0 + row) * TD + dq);
            uint2 qp = make_uint2(pack_rhu(qv.x * qscale, qv.y * qscale),
                                  pack_rhu(qv.z * qscale, qv.w * qscale));
            *(uint2*)&Qt[row][dq] = qp;
            float4 kv = *(const float4*)(Kg + hoff + (size_t)(j0 + row) * TD + dq);
            uint2 kp = make_uint2(pack_rhu(kv.x, kv.y), pack_rhu(kv.z, kv.w));
            *(uint2*)&Kt[row][dq] = kp;
        }
        __syncthreads();

        f32x4 sc[4][4];
        #pragma unroll
        for (int mt = 0; mt < 4; ++mt)
            #pragma unroll
            for (int nt = 0; nt < 4; ++nt) sc[mt][nt] = (f32x4){0.f, 0.f, 0.f, 0.f};
        #pragma unroll
        for (int ks = 0; ks < 2; ++ks) {
            bf16x8 af[4], bf[4];
            #pragma unroll
            for (int mt = 0; mt < 4; ++mt)
                af[mt] = *(const bf16x8*)&Qt[wq + mt * 16 + t16][ks * 32 + quad * 8];
            #pragma unroll
            for (int nt = 0; nt < 4; ++nt)
                bf[nt] = *(const bf16x8*)&Kt[wj + nt * 16 + t16][ks * 32 + quad * 8];
            #pragma unroll
            for (int mt = 0; mt < 4; ++mt)
                #pragma unroll
                for (int nt = 0; nt < 4; ++nt)
                    sc[mt][nt] = __builtin_amdgcn_mfma_f32_16x16x32_bf16(af[mt], bf[nt], sc[mt][nt], 0, 0, 0);
        }

        #pragma unroll
        for (int mt = 0; mt < 4; ++mt) {
            const int rl = wq + mt * 16 + quad * 4;
            const float lv[4] = {ML[h][rl], ML[h][rl + 1], ML[h][rl + 2], ML[h][rl + 3]};
            #pragma unroll
            for (int nt = 0; nt < 4; ++nt)
                #pragma unroll
                for (int r = 0; r < 4; ++r)
                    acc[mt][nt][r] = fmaf(__builtin_amdgcn_exp2f(sc[mt][nt][r]), lv[r], acc[mt][nt][r]);
        }
    }

    const float inv_h = 1.0f / (float)TH;
    #pragma unroll
    for (int mt = 0; mt < 4; ++mt) {
        #pragma unroll
        for (int r = 0; r < 4; ++r) {
            const int row = q0 + wq + mt * 16 + quad * 4 + r;
            #pragma unroll
            for (int nt = 0; nt < 4; ++nt) {
                const int col = j0 + wj + nt * 16 + t16;
                AV[((size_t)b * TS + row) * TS + col] = acc[mt][nt][r] * inv_h;
            }
        }
    }
}

// ----------------------------------------------------------------------------
extern "C" void kernel_launch(void* const* d_in, const int* in_sizes, int n_in,
                              void* d_out, int out_size, void* d_ws, size_t ws_size,
                              hipStream_t stream)
{
    const float* query = (const float*)d_in[0];
    const float* key   = (const float*)d_in[1];
    const float* value = (const float*)d_in[2];
    const float* Wq = (const float*)d_in[3];
    const float* bq = (const float*)d_in[4];
    const float* Wk = (const float*)d_in[5];
    const float* bk = (const float*)d_in[6];
    const float* Wv = (const float*)d_in[7];
    const float* bv = (const float*)d_in[8];
    const float* Wo = (const float*)d_in[9];
    const float* bo = (const float*)d_in[10];

    float* ws  = (float*)d_ws;
    float* Qr  = ws + WS_Q;       // RoPE'd Q fp32 [B,H,S,D]
    float* Kr  = ws + WS_K;       // RoPE'd K fp32 [B,H,S,D]
    float* Lsf = ws + WS_L;       // softmax denominators [B,H,S]
    float* tab = ws + WS_TAB;     // cos/sin

    float* out  = (float*)d_out;                   // [B,S,E]
    float* attn = out + (size_t)TB * TS * TE;      // [B,S,S] (written last)
    // park bf16 V^T and pre-projection O in the attn region (dead by attn_avg)
    short* VT = (short*)attn;                      // bf16 [B,H,D,S] = 4.2M floats
    float* Ow = attn + 4194304;                    // fp32 [B,S,E]   = 8.4M floats

    dim3 blk(256);
    dim3 gproj(TE / 128, TM_ / 128);

    gemm_nt<1><<<gproj, blk, 0, stream>>>(query, Wq, bq, Qr);
    gemm_nt<1><<<gproj, blk, 0, stream>>>(key,   Wk, bk, Kr);
    gemm_nt<2><<<gproj, blk, 0, stream>>>(value, Wv, bv, (float*)VT);
    rope_table<<<dim3(256), blk, 0, stream>>>(tab);
    rope_apply<<<dim3(32768), blk, 0, stream>>>(Qr, Kr, tab);
    attn_flash<<<dim3(TS / 128, TH, TB), dim3(512), 0, stream>>>(Qr, Kr, VT, Ow, Lsf);
    gemm_nt<0><<<gproj, blk, 0, stream>>>(Ow, Wo, bo, out);
    attn_avg_k<<<dim3(TS / 128, TS / 128, TB), blk, 0, stream>>>(Qr, Kr, Lsf, attn);
}